// Round 4
// baseline (44.434 us; speedup 1.0000x reference)
//
#include <hip/hip_runtime.h>
#include <hip/hip_bf16.h>
#include <stdint.h>

// GPTQ 4-bit fused dequant + GEMM.  x[128,4096]f32 @ W[4096,11008] -> out[128,11008]f32
// W[k][n] = scales[k/128][n] * nibble(qweight[k/8][n], k%8) - zeros[k/128][n]
//
// R4: SPLIT=8 (1376 blocks, ~5.4 waves/SIMD) + 2-deep register prefetch
//     (named sets aP0/aP1, fully unrolled KSC=8 loop -> static indexing).
//     Latency model: load->use distance ~2 iterations (~800cyc) ~= HBM latency.

#define IN_F   4096
#define OUT_F  11008
#define BATCH  128
#define BK     64
#define BN     64
#define NCHUNK (IN_F / BK)      // 64
#define SPLIT  8
#define KSC    (NCHUNK / SPLIT) // 8 chunks per block
#define NBLK   (OUT_F / BN)     // 172
#define MN     (BATCH * OUT_F)  // 1409024

typedef __attribute__((ext_vector_type(8))) short short8;
typedef __attribute__((ext_vector_type(4))) float f32x4;

static __device__ __forceinline__ unsigned int f2bf_pack(float lo, float hi) {
  unsigned int a = __float_as_uint(lo);
  unsigned int b = __float_as_uint(hi);
  a += 0x7FFFu + ((a >> 16) & 1u);
  b += 0x7FFFu + ((b >> 16) & 1u);
  return (a >> 16) | (b & 0xFFFF0000u);
}

__global__ __launch_bounds__(256) void cvt_kernel(const float* __restrict__ x,
                                                  unsigned int* __restrict__ xb) {
  int i = blockIdx.x * 256 + threadIdx.x;
  float4 v0 = *(const float4*)(x + (size_t)i * 8);
  float4 v1 = *(const float4*)(x + (size_t)i * 8 + 4);
  uint4 o;
  o.x = f2bf_pack(v0.x, v0.y);
  o.y = f2bf_pack(v0.z, v0.w);
  o.z = f2bf_pack(v1.x, v1.y);
  o.w = f2bf_pack(v1.z, v1.w);
  *(uint4*)(xb + (size_t)i * 4) = o;
}

__global__ __launch_bounds__(256) void zero_out(float* __restrict__ out) {
  int base = (blockIdx.x * 256 + threadIdx.x) * 16;   // 344 blocks
  float4 z = {0.f, 0.f, 0.f, 0.f};
#pragma unroll
  for (int j = 0; j < 4; ++j) *(float4*)(out + base + j * 4) = z;
}

__global__ __launch_bounds__(256) void reduce_kernel(const float* __restrict__ part,
                                                     float* __restrict__ out) {
  int base = (blockIdx.x * 256 + threadIdx.x) * 8;    // 688 blocks
  float4 s0 = {0.f, 0.f, 0.f, 0.f}, s1 = s0;
#pragma unroll
  for (int s = 0; s < SPLIT; ++s) {
    const float* p = part + (size_t)s * MN + base;
    float4 a = *(const float4*)(p);
    float4 b = *(const float4*)(p + 4);
    s0.x += a.x; s0.y += a.y; s0.z += a.z; s0.w += a.w;
    s1.x += b.x; s1.y += b.y; s1.z += b.z; s1.w += b.w;
  }
  *(float4*)(out + base)     = s0;
  *(float4*)(out + base + 4) = s1;
}

// ---- macros: static-index load/store of one K-chunk ----
#define LOAD_CHUNK(AP, QP, CH) do {                                            \
    const int k0_ = (CH) * BK;                                                 \
    _Pragma("unroll")                                                          \
    for (int i_ = 0; i_ < 4; ++i_) {                                           \
      int seg_ = tid + 256 * i_, row_ = seg_ >> 3, sc_ = seg_ & 7;             \
      if (use_xb) {                                                            \
        AP[i_] = *(const uint4*)(xb + (size_t)row_ * IN_F + k0_ + sc_ * 8);    \
      } else {                                                                 \
        const float* p_ = x + (size_t)row_ * IN_F + k0_ + sc_ * 8;             \
        float4 u0_ = *(const float4*)(p_);                                     \
        float4 u1_ = *(const float4*)(p_ + 4);                                 \
        AP[i_].x = f2bf_pack(u0_.x, u0_.y);                                    \
        AP[i_].y = f2bf_pack(u0_.z, u0_.w);                                    \
        AP[i_].z = f2bf_pack(u1_.x, u1_.y);                                    \
        AP[i_].w = f2bf_pack(u1_.z, u1_.w);                                    \
      }                                                                        \
    }                                                                          \
    _Pragma("unroll")                                                          \
    for (int i_ = 0; i_ < 2; ++i_) {                                           \
      QP[i_] = (unsigned int)qweight[(size_t)(k0_ / 8 + wid + 4 * i_) * OUT_F  \
                                     + n0 + col];                              \
    }                                                                          \
  } while (0)

#define STORE_CHUNK(AP, QP, CC) do {                                           \
    _Pragma("unroll")                                                          \
    for (int i_ = 0; i_ < 4; ++i_) {                                           \
      int seg_ = tid + 256 * i_, row_ = seg_ >> 3, sc_ = seg_ & 7;             \
      *(uint4*)(aLds + row_ * 128 + ((sc_ * 16) ^ ((row_ & 7) << 4))) = AP[i_];\
    }                                                                          \
    {                                                                          \
      float s_ = sreg[(CC) >> 1], z_ = zreg[(CC) >> 1];                        \
      _Pragma("unroll")                                                        \
      for (int i_ = 0; i_ < 2; ++i_) {                                         \
        unsigned int q_ = QP[i_];                                              \
        int qr_ = wid + 4 * i_;                                                \
        float f0_ = s_ * (float)((q_ >> 0)  & 0xFu) - z_;                      \
        float f1_ = s_ * (float)((q_ >> 4)  & 0xFu) - z_;                      \
        float f2_ = s_ * (float)((q_ >> 8)  & 0xFu) - z_;                      \
        float f3_ = s_ * (float)((q_ >> 12) & 0xFu) - z_;                      \
        float f4_ = s_ * (float)((q_ >> 16) & 0xFu) - z_;                      \
        float f5_ = s_ * (float)((q_ >> 20) & 0xFu) - z_;                      \
        float f6_ = s_ * (float)((q_ >> 24) & 0xFu) - z_;                      \
        float f7_ = s_ * (float)((q_ >> 28) & 0xFu) - z_;                      \
        uint4 v_;                                                              \
        v_.x = f2bf_pack(f0_, f1_);                                            \
        v_.y = f2bf_pack(f2_, f3_);                                            \
        v_.z = f2bf_pack(f4_, f5_);                                            \
        v_.w = f2bf_pack(f6_, f7_);                                            \
        *(uint4*)(bLds + col * 128 + ((qr_ * 16) ^ ((col & 7) << 4))) = v_;    \
      }                                                                        \
    }                                                                          \
  } while (0)

__global__ __launch_bounds__(256) void gptq_gemm(
    const unsigned short* __restrict__ xb,  // [128,4096] bf16 (may be unused)
    const float* __restrict__ x,            // [128,4096] f32 fallback
    const int* __restrict__ qweight,        // [512, 11008]
    const float* __restrict__ scales,       // [32, 11008]
    const float* __restrict__ zeros,        // [32, 11008]
    float* __restrict__ outp,               // out (atomic) or partials base
    int use_xb, int atomic_mode) {
  // A tile: 128 rows x 64 bf16 (128B/row), XOR-swizzled: byte ^= (row&7)<<4
  // B tile: 64 cols x 64 bf16 (col-major, 128B/col), same swizzle on col
  __shared__ char aLds[BATCH * 128];
  __shared__ char bLds[BN * 128];

  const int tid  = threadIdx.x;
  const int lane = tid & 63;
  const int wid  = tid >> 6;
  const int wr   = wid >> 1;   // 0..1 : row half (64 rows)
  const int wc   = wid & 1;    // 0..1 : col half (32 cols)
  const int nb   = blockIdx.x % NBLK;
  const int sl   = blockIdx.x / NBLK;
  const int n0   = nb * BN;
  const int c0   = sl * KSC;   // first chunk of this K-slice

  float* dst = atomic_mode ? outp : outp + (size_t)sl * MN;

  // hoist scales/zeros for the 4 groups this K-slice covers (group = 2 chunks)
  const int col = tid & 63;
  const int g0  = c0 >> 1;
  float sreg[KSC / 2], zreg[KSC / 2];
#pragma unroll
  for (int g = 0; g < KSC / 2; ++g) {
    sreg[g] = scales[(size_t)(g0 + g) * OUT_F + n0 + col];
    zreg[g] = zeros [(size_t)(g0 + g) * OUT_F + n0 + col];
  }

  // ---- 2-deep prefetch: two named register sets ----
  uint4 aP0[4], aP1[4];
  unsigned int qP0[2], qP1[2];
  LOAD_CHUNK(aP0, qP0, c0);
  LOAD_CHUNK(aP1, qP1, c0 + 1);

  f32x4 acc[4][2] = {};

#pragma unroll
  for (int cc = 0; cc < KSC; ++cc) {
    __syncthreads();   // previous chunk's consumers done with LDS

    if ((cc & 1) == 0) {
      STORE_CHUNK(aP0, qP0, cc);
      if (cc + 2 < KSC) LOAD_CHUNK(aP0, qP0, c0 + cc + 2);
    } else {
      STORE_CHUNK(aP1, qP1, cc);
      if (cc + 2 < KSC) LOAD_CHUNK(aP1, qP1, c0 + cc + 2);
    }
    __syncthreads();

    // ---- compute: 2 k-steps of 32 ----
#pragma unroll
    for (int ks = 0; ks < 2; ++ks) {
      int kbyte = ks * 64 + ((lane >> 4) << 4);
      short8 bfrag[2];
#pragma unroll
      for (int ct = 0; ct < 2; ++ct) {
        int c = wc * 32 + ct * 16 + (lane & 15);
        bfrag[ct] = *(const short8*)(bLds + c * 128 + (kbyte ^ ((c & 7) << 4)));
      }
#pragma unroll
      for (int rt = 0; rt < 4; ++rt) {
        int row = wr * 64 + rt * 16 + (lane & 15);
        short8 afrag = *(const short8*)(aLds + row * 128 + (kbyte ^ ((row & 7) << 4)));
#pragma unroll
        for (int ct = 0; ct < 2; ++ct) {
          acc[rt][ct] = __builtin_amdgcn_mfma_f32_16x16x32_bf16(afrag, bfrag[ct], acc[rt][ct], 0, 0, 0);
        }
      }
    }
  }

  // ---- epilogue: C/D layout col=lane&15, row=(lane>>4)*4+reg ----
#pragma unroll
  for (int rt = 0; rt < 4; ++rt) {
#pragma unroll
    for (int ct = 0; ct < 2; ++ct) {
      int c = n0 + wc * 32 + ct * 16 + (lane & 15);
#pragma unroll
      for (int r = 0; r < 4; ++r) {
        int row = wr * 64 + rt * 16 + ((lane >> 4) << 2) + r;
        if (atomic_mode) {
          atomicAdd(dst + (size_t)row * OUT_F + c, acc[rt][ct][r]);
        } else {
          dst[(size_t)row * OUT_F + c] = acc[rt][ct][r];
        }
      }
    }
  }
}

extern "C" void kernel_launch(void* const* d_in, const int* in_sizes, int n_in,
                              void* d_out, int out_size, void* d_ws, size_t ws_size,
                              hipStream_t stream) {
  const float* x       = (const float*)d_in[0];
  const int*   qweight = (const int*)d_in[1];
  const float* scales  = (const float*)d_in[2];
  const float* zeros   = (const float*)d_in[3];
  float*       outp    = (float*)d_out;

  const size_t xb_bytes   = (size_t)BATCH * IN_F * sizeof(unsigned short);  // 1 MB
  const size_t part_bytes = (size_t)SPLIT * MN * sizeof(float);             // 45 MB
  int use_xb   = (ws_size >= xb_bytes) ? 1 : 0;
  int partials = (ws_size >= xb_bytes + part_bytes) ? 1 : 0;

  unsigned short* xb   = (unsigned short*)d_ws;
  float*          part = (float*)((char*)d_ws + xb_bytes);

  if (use_xb) {
    cvt_kernel<<<256, 256, 0, stream>>>(x, (unsigned int*)d_ws);
  }

  if (partials) {
    gptq_gemm<<<NBLK * SPLIT, 256, 0, stream>>>(xb, x, qweight, scales, zeros,
                                                part, use_xb, 0);
    reduce_kernel<<<688, 256, 0, stream>>>(part, outp);
  } else {
    zero_out<<<344, 256, 0, stream>>>(outp);
    gptq_gemm<<<NBLK * SPLIT, 256, 0, stream>>>(xb, x, qweight, scales, zeros,
                                                outp, use_xb, 1);
  }
}

// Round 5
// 40.775 us; speedup vs baseline: 1.0897x; 1.0897x over previous
//
#include <hip/hip_runtime.h>
#include <hip/hip_bf16.h>
#include <stdint.h>

// GPTQ 4-bit fused dequant + GEMM.  x[128,4096]f32 @ W[4096,11008] -> out[128,11008]f32
// W[k][n] = scales[k/128][n] * nibble(qweight[k/8][n], k%8) - zeros[k/128][n]
//
// R5: SPLIT=4 (halve partial tax vs R4) + LDS double-buffer 2-phase pipeline:
//     ONE barrier per chunk; per iter: {issue loads cc+2/cc+3 -> dequant+ds_write
//     chunk cc+1 into buf[p^1] -> ds_read+MFMA chunk cc from buf[p] -> barrier}.
//     qweight prefetch 3-deep (HBM ~900cyc), xb 2-deep (L2 ~200cyc).

#define IN_F   4096
#define OUT_F  11008
#define BATCH  128
#define BK     64
#define BN     64
#define NCHUNK (IN_F / BK)      // 64
#define SPLIT  4
#define KSC    (NCHUNK / SPLIT) // 16 chunks per block
#define NBLK   (OUT_F / BN)     // 172
#define MN     (BATCH * OUT_F)  // 1409024

typedef __attribute__((ext_vector_type(8))) short short8;
typedef __attribute__((ext_vector_type(4))) float f32x4;

static __device__ __forceinline__ unsigned int f2bf_pack(float lo, float hi) {
  unsigned int a = __float_as_uint(lo);
  unsigned int b = __float_as_uint(hi);
  a += 0x7FFFu + ((a >> 16) & 1u);
  b += 0x7FFFu + ((b >> 16) & 1u);
  return (a >> 16) | (b & 0xFFFF0000u);
}

__global__ __launch_bounds__(256) void cvt_kernel(const float* __restrict__ x,
                                                  unsigned int* __restrict__ xb) {
  int i = blockIdx.x * 256 + threadIdx.x;
  float4 v0 = *(const float4*)(x + (size_t)i * 8);
  float4 v1 = *(const float4*)(x + (size_t)i * 8 + 4);
  uint4 o;
  o.x = f2bf_pack(v0.x, v0.y);
  o.y = f2bf_pack(v0.z, v0.w);
  o.z = f2bf_pack(v1.x, v1.y);
  o.w = f2bf_pack(v1.z, v1.w);
  *(uint4*)(xb + (size_t)i * 4) = o;
}

__global__ __launch_bounds__(256) void zero_out(float* __restrict__ out) {
  int base = (blockIdx.x * 256 + threadIdx.x) * 16;   // 344 blocks
  float4 z = {0.f, 0.f, 0.f, 0.f};
#pragma unroll
  for (int j = 0; j < 4; ++j) *(float4*)(out + base + j * 4) = z;
}

__global__ __launch_bounds__(256) void reduce_kernel(const float* __restrict__ part,
                                                     float* __restrict__ out) {
  int base = (blockIdx.x * 256 + threadIdx.x) * 8;    // 688 blocks
  float4 s0 = {0.f, 0.f, 0.f, 0.f}, s1 = s0;
#pragma unroll
  for (int s = 0; s < SPLIT; ++s) {
    const float* p = part + (size_t)s * MN + base;
    float4 a = *(const float4*)(p);
    float4 b = *(const float4*)(p + 4);
    s0.x += a.x; s0.y += a.y; s0.z += a.z; s0.w += a.w;
    s1.x += b.x; s1.y += b.y; s1.z += b.z; s1.w += b.w;
  }
  *(float4*)(out + base)     = s0;
  *(float4*)(out + base + 4) = s1;
}

// ---- macros (all indices compile-time after full unroll) ----
#define LOAD_A(SET, CH) do {                                                   \
    const int k0_ = (CH) * BK;                                                 \
    _Pragma("unroll")                                                          \
    for (int i_ = 0; i_ < 4; ++i_) {                                           \
      int seg_ = tid + 256 * i_, row_ = seg_ >> 3, sc_ = seg_ & 7;             \
      if (use_xb) {                                                            \
        aP[SET][i_] = *(const uint4*)(xb + (size_t)row_ * IN_F + k0_ + sc_ * 8);\
      } else {                                                                 \
        const float* p_ = x + (size_t)row_ * IN_F + k0_ + sc_ * 8;             \
        float4 u0_ = *(const float4*)(p_);                                     \
        float4 u1_ = *(const float4*)(p_ + 4);                                 \
        aP[SET][i_].x = f2bf_pack(u0_.x, u0_.y);                               \
        aP[SET][i_].y = f2bf_pack(u0_.z, u0_.w);                               \
        aP[SET][i_].z = f2bf_pack(u1_.x, u1_.y);                               \
        aP[SET][i_].w = f2bf_pack(u1_.z, u1_.w);                               \
      }                                                                        \
    }                                                                          \
  } while (0)

#define LOAD_Q(SET, CH) do {                                                   \
    const int k0_ = (CH) * BK;                                                 \
    _Pragma("unroll")                                                          \
    for (int i_ = 0; i_ < 2; ++i_) {                                           \
      qP[SET][i_] = (unsigned int)qweight[(size_t)(k0_ / 8 + wid + 4 * i_) * OUT_F \
                                          + n0 + col];                         \
    }                                                                          \
  } while (0)

// dequant qP[QS] + store aP[AS] into buffer PB; GI = local group index
#define STORE_CHUNK(PB, AS, QS, GI) do {                                       \
    char* aB_ = aLds + (PB) * (BATCH * 128);                                   \
    char* bB_ = bLds + (PB) * (BN * 128);                                      \
    _Pragma("unroll")                                                          \
    for (int i_ = 0; i_ < 4; ++i_) {                                           \
      int seg_ = tid + 256 * i_, row_ = seg_ >> 3, sc_ = seg_ & 7;             \
      *(uint4*)(aB_ + row_ * 128 + ((sc_ * 16) ^ ((row_ & 7) << 4))) = aP[AS][i_];\
    }                                                                          \
    {                                                                          \
      float s_ = sreg[GI], z_ = zreg[GI];                                      \
      _Pragma("unroll")                                                        \
      for (int i_ = 0; i_ < 2; ++i_) {                                         \
        unsigned int q_ = qP[QS][i_];                                          \
        int qr_ = wid + 4 * i_;                                                \
        float f0_ = s_ * (float)((q_ >> 0)  & 0xFu) - z_;                      \
        float f1_ = s_ * (float)((q_ >> 4)  & 0xFu) - z_;                      \
        float f2_ = s_ * (float)((q_ >> 8)  & 0xFu) - z_;                      \
        float f3_ = s_ * (float)((q_ >> 12) & 0xFu) - z_;                      \
        float f4_ = s_ * (float)((q_ >> 16) & 0xFu) - z_;                      \
        float f5_ = s_ * (float)((q_ >> 20) & 0xFu) - z_;                      \
        float f6_ = s_ * (float)((q_ >> 24) & 0xFu) - z_;                      \
        float f7_ = s_ * (float)((q_ >> 28) & 0xFu) - z_;                      \
        uint4 v_;                                                              \
        v_.x = f2bf_pack(f0_, f1_);                                            \
        v_.y = f2bf_pack(f2_, f3_);                                            \
        v_.z = f2bf_pack(f4_, f5_);                                            \
        v_.w = f2bf_pack(f6_, f7_);                                            \
        *(uint4*)(bB_ + col * 128 + ((qr_ * 16) ^ ((col & 7) << 4))) = v_;     \
      }                                                                        \
    }                                                                          \
  } while (0)

#define COMPUTE(PB) do {                                                       \
    const char* aB_ = aLds + (PB) * (BATCH * 128);                             \
    const char* bB_ = bLds + (PB) * (BN * 128);                                \
    _Pragma("unroll")                                                          \
    for (int ks_ = 0; ks_ < 2; ++ks_) {                                        \
      int kb_ = ks_ * 64 + ((lane >> 4) << 4);                                 \
      short8 bf_[2];                                                           \
      _Pragma("unroll")                                                        \
      for (int ct_ = 0; ct_ < 2; ++ct_) {                                      \
        int c_ = wc * 32 + ct_ * 16 + (lane & 15);                             \
        bf_[ct_] = *(const short8*)(bB_ + c_ * 128 + (kb_ ^ ((c_ & 7) << 4))); \
      }                                                                        \
      _Pragma("unroll")                                                        \
      for (int rt_ = 0; rt_ < 4; ++rt_) {                                      \
        int r_ = wr * 64 + rt_ * 16 + (lane & 15);                             \
        short8 af_ = *(const short8*)(aB_ + r_ * 128 + (kb_ ^ ((r_ & 7) << 4)));\
        _Pragma("unroll")                                                      \
        for (int ct_ = 0; ct_ < 2; ++ct_) {                                    \
          acc[rt_][ct_] = __builtin_amdgcn_mfma_f32_16x16x32_bf16(             \
              af_, bf_[ct_], acc[rt_][ct_], 0, 0, 0);                          \
        }                                                                      \
      }                                                                        \
    }                                                                          \
  } while (0)

__global__ __launch_bounds__(256) void gptq_gemm(
    const unsigned short* __restrict__ xb,  // [128,4096] bf16 (may be unused)
    const float* __restrict__ x,            // [128,4096] f32 fallback
    const int* __restrict__ qweight,        // [512, 11008]
    const float* __restrict__ scales,       // [32, 11008]
    const float* __restrict__ zeros,        // [32, 11008]
    float* __restrict__ outp,               // out (atomic) or partials base
    int use_xb, int atomic_mode) {
  // double-buffered: A 128x64 bf16 (128B/row) x2, B 64x64 (col-major) x2; swizzle byte^=(idx&7)<<4
  __shared__ char aLds[2 * BATCH * 128];   // 32 KB
  __shared__ char bLds[2 * BN * 128];      // 16 KB

  const int tid  = threadIdx.x;
  const int lane = tid & 63;
  const int wid  = tid >> 6;
  const int wr   = wid >> 1;
  const int wc   = wid & 1;
  const int nb   = blockIdx.x % NBLK;
  const int sl   = blockIdx.x / NBLK;
  const int n0   = nb * BN;
  const int c0   = sl * KSC;   // first chunk of this K-slice (even)

  float* dst = atomic_mode ? outp : outp + (size_t)sl * MN;

  const int col = tid & 63;
  const int g0  = c0 >> 1;
  float sreg[KSC / 2], zreg[KSC / 2];
#pragma unroll
  for (int g = 0; g < KSC / 2; ++g) {
    sreg[g] = scales[(size_t)(g0 + g) * OUT_F + n0 + col];
    zreg[g] = zeros [(size_t)(g0 + g) * OUT_F + n0 + col];
  }

  uint4 aP[2][4];
  unsigned int qP[3][2];

  // ---- prologue: A 2-deep, Q 3-deep; stage chunk 0 into buf0 ----
  LOAD_A(0, c0);
  LOAD_A(1, c0 + 1);
  LOAD_Q(0, c0);
  LOAD_Q(1, c0 + 1);
  LOAD_Q(2, c0 + 2);
  STORE_CHUNK(0, 0, 0, 0);
  __syncthreads();

  f32x4 acc[4][2] = {};

  // invariant at top of iter cc: buf[cc&1] = chunk cc; aP[(cc+1)&1] = chunk cc+1;
  //                              qP[(cc+1)%3], qP[(cc+2)%3] = chunks cc+1, cc+2
#pragma unroll
  for (int cc = 0; cc < KSC; ++cc) {
    const int p = cc & 1;
    if (cc + 2 < KSC) LOAD_A(p, c0 + cc + 2);          // reuse just-freed set
    if (cc + 3 < KSC) LOAD_Q((cc) % 3, c0 + cc + 3);   // (cc+3)%3 == cc%3
    if (cc + 1 < KSC) STORE_CHUNK(p ^ 1, p ^ 1, (cc + 1) % 3, (cc + 1) >> 1);
    COMPUTE(p);
    if (cc + 1 < KSC) __syncthreads();
  }

  // ---- epilogue: C/D layout col=lane&15, row=(lane>>4)*4+reg ----
#pragma unroll
  for (int rt = 0; rt < 4; ++rt) {
#pragma unroll
    for (int ct = 0; ct < 2; ++ct) {
      int c = n0 + wc * 32 + ct * 16 + (lane & 15);
#pragma unroll
      for (int r = 0; r < 4; ++r) {
        int row = wr * 64 + rt * 16 + ((lane >> 4) << 2) + r;
        if (atomic_mode) {
          atomicAdd(dst + (size_t)row * OUT_F + c, acc[rt][ct][r]);
        } else {
          dst[(size_t)row * OUT_F + c] = acc[rt][ct][r];
        }
      }
    }
  }
}

extern "C" void kernel_launch(void* const* d_in, const int* in_sizes, int n_in,
                              void* d_out, int out_size, void* d_ws, size_t ws_size,
                              hipStream_t stream) {
  const float* x       = (const float*)d_in[0];
  const int*   qweight = (const int*)d_in[1];
  const float* scales  = (const float*)d_in[2];
  const float* zeros   = (const float*)d_in[3];
  float*       outp    = (float*)d_out;

  const size_t xb_bytes   = (size_t)BATCH * IN_F * sizeof(unsigned short);  // 1 MB
  const size_t part_bytes = (size_t)SPLIT * MN * sizeof(float);             // 22.5 MB
  int use_xb   = (ws_size >= xb_bytes) ? 1 : 0;
  int partials = (ws_size >= xb_bytes + part_bytes) ? 1 : 0;

  unsigned short* xb   = (unsigned short*)d_ws;
  float*          part = (float*)((char*)d_ws + xb_bytes);

  if (use_xb) {
    cvt_kernel<<<256, 256, 0, stream>>>(x, (unsigned int*)d_ws);
  }

  if (partials) {
    gptq_gemm<<<NBLK * SPLIT, 256, 0, stream>>>(xb, x, qweight, scales, zeros,
                                                part, use_xb, 0);
    reduce_kernel<<<688, 256, 0, stream>>>(part, outp);
  } else {
    zero_out<<<344, 256, 0, stream>>>(outp);
    gptq_gemm<<<NBLK * SPLIT, 256, 0, stream>>>(xb, x, qweight, scales, zeros,
                                                outp, use_xb, 1);
  }
}